// Round 1
// baseline (939.571 us; speedup 1.0000x reference)
//
#include <hip/hip_runtime.h>
#include <hip/hip_bf16.h>
#include <math.h>

constexpr int Bsz = 64, Cctx = 200, Hdim = 1024, Edim = 1024, Vv = 50257;
constexpr float NEG_INF_V = -100000.0f;

typedef __attribute__((ext_vector_type(8))) short s16x8;
typedef __attribute__((ext_vector_type(4))) short s16x4;
typedef __attribute__((ext_vector_type(4))) float fx4;

__device__ __forceinline__ unsigned short f2bf(float f) {
  unsigned int u = __builtin_bit_cast(unsigned int, f);
  unsigned int r = (u + 0x7fffu + ((u >> 16) & 1u)) >> 16;
  return (unsigned short)r;
}

// C = A(M,K) * B(N,K)^T, f32 inputs staged to LDS as bf16, fp32 MFMA accum.
// EPI 0: store f32 to Cout (ld=N). EPI 2: store f32 + bias[n].
// EPI 1: t = tanh(acc + q[m%64, n]); rowsum += t*v[n]; atomicAdd(scores[(m%64)*C + m/64]).
template<int BM, int BN, int EPI>
__global__ __launch_bounds__(256)
void gemm_nt(const float* __restrict__ A, const float* __restrict__ Bm,
             int M, int N, int K,
             const float* __restrict__ bias,
             float* __restrict__ Cout,
             const float* __restrict__ qmat,
             const float* __restrict__ vvec,
             float* __restrict__ scores)
{
  constexpr int BK = 64;
  constexpr int LDT = BK + 8;           // +8 bf16 pad (16B) keeps b128 reads ~2-way
  constexpr int WM = BM / 2, WN = BN / 2;
  constexpr int FM = WM / 16, FN = WN / 16;

  __shared__ unsigned short As[BM][LDT];
  __shared__ unsigned short Bs[BN][LDT];

  const int tid = threadIdx.x;
  const int lane = tid & 63;
  const int wid = tid >> 6;
  const int wr = wid >> 1, wc = wid & 1;
  const int wm0 = wr * WM, wn0 = wc * WN;
  const int ar = lane & 15;             // row within 16-tile (A) / col (B)
  const int ak = (lane >> 4) * 8;       // k offset within K=32 step
  const int bm0 = blockIdx.y * BM, bn0 = blockIdx.x * BN;

  fx4 acc[FM][FN] = {};

  for (int kt = 0; kt < K; kt += BK) {
    // stage A: BM x 64 f32 -> bf16
    #pragma unroll
    for (int i = 0; i < BM / 16; ++i) {
      int f = tid + i * 256;
      int row = f >> 4, c4 = f & 15;
      int gr = bm0 + row;
      float4 val = make_float4(0.f, 0.f, 0.f, 0.f);
      if (gr < M) val = *reinterpret_cast<const float4*>(&A[(size_t)gr * K + kt + c4 * 4]);
      s16x4 h;
      h[0] = (short)f2bf(val.x); h[1] = (short)f2bf(val.y);
      h[2] = (short)f2bf(val.z); h[3] = (short)f2bf(val.w);
      *reinterpret_cast<s16x4*>(&As[row][c4 * 4]) = h;
    }
    // stage B: BN x 64 f32 -> bf16
    #pragma unroll
    for (int i = 0; i < BN / 16; ++i) {
      int f = tid + i * 256;
      int row = f >> 4, c4 = f & 15;
      int gr = bn0 + row;
      float4 val = make_float4(0.f, 0.f, 0.f, 0.f);
      if (gr < N) val = *reinterpret_cast<const float4*>(&Bm[(size_t)gr * K + kt + c4 * 4]);
      s16x4 h;
      h[0] = (short)f2bf(val.x); h[1] = (short)f2bf(val.y);
      h[2] = (short)f2bf(val.z); h[3] = (short)f2bf(val.w);
      *reinterpret_cast<s16x4*>(&Bs[row][c4 * 4]) = h;
    }
    __syncthreads();
    #pragma unroll
    for (int kk = 0; kk < 2; ++kk) {
      s16x8 a[FM], b[FN];
      #pragma unroll
      for (int i = 0; i < FM; ++i)
        a[i] = *reinterpret_cast<const s16x8*>(&As[wm0 + i * 16 + ar][kk * 32 + ak]);
      #pragma unroll
      for (int j = 0; j < FN; ++j)
        b[j] = *reinterpret_cast<const s16x8*>(&Bs[wn0 + j * 16 + ar][kk * 32 + ak]);
      #pragma unroll
      for (int i = 0; i < FM; ++i)
        #pragma unroll
        for (int j = 0; j < FN; ++j)
          acc[i][j] = __builtin_amdgcn_mfma_f32_16x16x32_bf16(a[i], b[j], acc[i][j], 0, 0, 0);
    }
    __syncthreads();
  }

  const int rg = (lane >> 4) * 4;       // row base within 16-tile
  const int cg = lane & 15;             // col within 16-tile

  if constexpr (EPI == 1) {
    #pragma unroll
    for (int i = 0; i < FM; ++i) {
      #pragma unroll
      for (int p = 0; p < 4; ++p) {
        int mg = bm0 + wm0 + i * 16 + rg + p;
        int brow = mg & 63;             // b index (M rows are (c,b), B=64)
        float rs = 0.f;
        #pragma unroll
        for (int j = 0; j < FN; ++j) {
          int ng = bn0 + wn0 + j * 16 + cg;
          float t = tanhf(acc[i][j][p] + qmat[brow * Hdim + ng]);
          rs += t * vvec[ng];
        }
        rs += __shfl_xor(rs, 1);
        rs += __shfl_xor(rs, 2);
        rs += __shfl_xor(rs, 4);
        rs += __shfl_xor(rs, 8);
        if (cg == 0) {
          int c = mg >> 6;
          atomicAdd(&scores[brow * Cctx + c], rs);
        }
      }
    }
  } else {
    #pragma unroll
    for (int i = 0; i < FM; ++i) {
      #pragma unroll
      for (int p = 0; p < 4; ++p) {
        int mg = bm0 + wm0 + i * 16 + rg + p;
        if (mg < M) {
          #pragma unroll
          for (int j = 0; j < FN; ++j) {
            int ng = bn0 + wn0 + j * 16 + cg;
            if (ng < N) {
              float o = acc[i][j][p];
              if constexpr (EPI == 2) o += bias[ng];
              Cout[(size_t)mg * N + ng] = o;
            }
          }
        }
      }
    }
  }
}

__global__ void transpose1024(const float* __restrict__ in, float* __restrict__ out) {
  __shared__ float t[32][33];
  int tx = threadIdx.x, ty = threadIdx.y;   // 32 x 8
  int bx = blockIdx.x * 32, by = blockIdx.y * 32;
  #pragma unroll
  for (int r = 0; r < 32; r += 8)
    t[ty + r][tx] = in[(size_t)(by + ty + r) * 1024 + bx + tx];
  __syncthreads();
  #pragma unroll
  for (int r = 0; r < 32; r += 8)
    out[(size_t)(bx + ty + r) * 1024 + by + tx] = t[tx][ty + r];
}

__global__ __launch_bounds__(256)
void softmax_pad(const float* __restrict__ scores, const int* __restrict__ pad,
                 float* __restrict__ attn) {
  int b = blockIdx.x, t = threadIdx.x;
  int lane = t & 63, wid = t >> 6;
  __shared__ float red[8];
  float sv = 0.f;
  float v = -3.4e38f;
  if (t < Cctx) {
    sv = pad[b * Cctx + t] ? NEG_INF_V : scores[b * Cctx + t];
    v = sv;
  }
  #pragma unroll
  for (int o = 1; o < 64; o <<= 1) v = fmaxf(v, __shfl_xor(v, o));
  if (lane == 0) red[wid] = v;
  __syncthreads();
  float m = fmaxf(fmaxf(red[0], red[1]), fmaxf(red[2], red[3]));
  float e = (t < Cctx) ? expf(sv - m) : 0.f;
  float s = e;
  #pragma unroll
  for (int o = 1; o < 64; o <<= 1) s += __shfl_xor(s, o);
  if (lane == 0) red[4 + wid] = s;
  __syncthreads();
  float tot = red[4] + red[5] + red[6] + red[7];
  if (t < Cctx) attn[b * Cctx + t] = e / tot;
}

__global__ void build_x(const float* __restrict__ inp, const float* __restrict__ topic,
                        float* __restrict__ x) {
  int idx = blockIdx.x * blockDim.x + threadIdx.x;   // 64*2048
  int b = idx >> 11, j = idx & 2047;
  float v = (j < 1024) ? inp[b * 1024 + j] : topic[b * 1024 + (j - 1024)];
  x[(size_t)b * 3072 + j] = v;
}

__global__ __launch_bounds__(256)
void applied_k(const float* __restrict__ attn, const float* __restrict__ ch,
               float* __restrict__ x) {
  int b = blockIdx.y;
  int h = blockIdx.x * 256 + threadIdx.x;
  __shared__ float at[256];
  at[threadIdx.x] = (threadIdx.x < Cctx) ? attn[b * Cctx + threadIdx.x] : 0.f;
  __syncthreads();
  float acc = 0.f;
  const float* p = &ch[(size_t)b * Cctx * Hdim + h];
  #pragma unroll 4
  for (int c = 0; c < Cctx; ++c) acc += at[c] * p[(size_t)c * Hdim];
  x[(size_t)b * 3072 + 2048 + h] = acc;
}

__global__ void gru_gate(const float* __restrict__ gi, const float* __restrict__ gh,
                         const float* __restrict__ h0, float* __restrict__ hnew,
                         float* __restrict__ out_h) {
  int idx = blockIdx.x * blockDim.x + threadIdx.x;   // B*H = 65536
  int b = idx >> 10, j = idx & 1023;
  const float* gib = gi + (size_t)b * 3072;
  const float* ghb = gh + (size_t)b * 3072;
  float r = 1.f / (1.f + expf(-(gib[j] + ghb[j])));
  float z = 1.f / (1.f + expf(-(gib[1024 + j] + ghb[1024 + j])));
  float n = tanhf(gib[2048 + j] + r * ghb[2048 + j]);
  float h = (1.f - z) * n + z * h0[idx];
  hnew[idx] = h;
  out_h[idx] = h;
}

__global__ __launch_bounds__(256)
void row_lse(const float* __restrict__ logits, float* __restrict__ lse) {
  int b = blockIdx.x, t = threadIdx.x;
  int lane = t & 63, wid = t >> 6;
  __shared__ float red[8];
  const float* row = logits + (size_t)b * Vv;
  float m = -3.4e38f;
  for (int i = t; i < Vv; i += 256) m = fmaxf(m, row[i]);
  #pragma unroll
  for (int o = 1; o < 64; o <<= 1) m = fmaxf(m, __shfl_xor(m, o));
  if (lane == 0) red[wid] = m;
  __syncthreads();
  m = fmaxf(fmaxf(red[0], red[1]), fmaxf(red[2], red[3]));
  float s = 0.f;
  for (int i = t; i < Vv; i += 256) s += expf(row[i] - m);
  #pragma unroll
  for (int o = 1; o < 64; o <<= 1) s += __shfl_xor(s, o);
  if (lane == 0) red[4 + wid] = s;
  __syncthreads();
  if (t == 0) lse[b] = m + logf(red[4] + red[5] + red[6] + red[7]);
}

__global__ void sub_lse(float* __restrict__ out, const float* __restrict__ lse) {
  int b = blockIdx.y;
  int i = blockIdx.x * 256 + threadIdx.x;
  if (i < Vv) out[(size_t)b * Vv + i] -= lse[b];
}

extern "C" void kernel_launch(void* const* d_in, const int* in_sizes, int n_in,
                              void* d_out, int out_size, void* d_ws, size_t ws_size,
                              hipStream_t stream) {
  const float* input  = (const float*)d_in[0];
  const float* hidden = (const float*)d_in[1];   // (1,B,H) == h0 (B,H)
  const float* lch    = (const float*)d_in[2];   // (C,B,H)
  const float* ch     = (const float*)d_in[3];   // (B,C,H)
  const float* topic  = (const float*)d_in[4];
  const int*   pad    = (const int*)d_in[5];
  const float* dyna_W = (const float*)d_in[6];
  const float* dyna_U = (const float*)d_in[7];
  const float* dyna_v = (const float*)d_in[8];
  const float* W_ih   = (const float*)d_in[9];
  const float* W_hh   = (const float*)d_in[10];
  const float* b_ih   = (const float*)d_in[11];
  const float* b_hh   = (const float*)d_in[12];
  const float* W_out  = (const float*)d_in[13];
  const float* b_out  = (const float*)d_in[14];

  float* out   = (float*)d_out;                    // (B,V) logits -> logprobs
  float* out_h = out + (size_t)Bsz * Vv;           // (B,H) h_new

  float* p = (float*)d_ws;
  float* Wt     = p; p += 1024 * 1024;
  float* Ut     = p; p += 1024 * 1024;
  float* q      = p; p += Bsz * Hdim;
  float* scores = p; p += Bsz * Cctx;
  float* attn   = p; p += Bsz * Cctx;
  float* x      = p; p += Bsz * 3072;
  float* gi     = p; p += Bsz * 3072;
  float* gh     = p; p += Bsz * 3072;
  float* hnew   = p; p += Bsz * Hdim;
  float* lse    = p; p += 64;

  dim3 tt(32, 8);
  transpose1024<<<dim3(32, 32), tt, 0, stream>>>(dyna_W, Wt);
  transpose1024<<<dim3(32, 32), tt, 0, stream>>>(dyna_U, Ut);
  hipMemsetAsync(scores, 0, Bsz * Cctx * sizeof(float), stream);

  // q = h0 @ dyna_W   (64 x 1024, K=1024)
  gemm_nt<64, 128, 0><<<dim3(8, 1), 256, 0, stream>>>(
      hidden, Wt, Bsz, Hdim, Hdim, nullptr, q, nullptr, nullptr, nullptr);

  // scores += tanh(q + lch@U) . v   (M = C*B = 12800)
  gemm_nt<128, 128, 1><<<dim3(8, 100), 256, 0, stream>>>(
      lch, Ut, Cctx * Bsz, Hdim, Hdim, nullptr, nullptr, q, dyna_v, scores);

  softmax_pad<<<Bsz, 256, 0, stream>>>(scores, pad, attn);

  build_x<<<(Bsz * 2048) / 256, 256, 0, stream>>>(input, topic, x);
  applied_k<<<dim3(4, Bsz), 256, 0, stream>>>(attn, ch, x);

  // gi = x @ W_ih^T + b_ih   (64 x 3072, K=3072)
  gemm_nt<64, 128, 2><<<dim3(24, 1), 256, 0, stream>>>(
      x, W_ih, Bsz, 3072, 3072, b_ih, gi, nullptr, nullptr, nullptr);
  // gh = h0 @ W_hh^T + b_hh  (64 x 3072, K=1024)
  gemm_nt<64, 128, 2><<<dim3(24, 1), 256, 0, stream>>>(
      hidden, W_hh, Bsz, 3072, Hdim, b_hh, gh, nullptr, nullptr, nullptr);

  gru_gate<<<(Bsz * Hdim) / 256, 256, 0, stream>>>(gi, gh, hidden, hnew, out_h);

  // logits = h_new @ W_out^T + b_out  (64 x 50257, K=1024) -> d_out
  gemm_nt<64, 128, 2><<<dim3((Vv + 127) / 128, 1), 256, 0, stream>>>(
      hnew, W_out, Bsz, Vv, Hdim, b_out, out, nullptr, nullptr, nullptr);

  row_lse<<<Bsz, 256, 0, stream>>>(out, lse);
  sub_lse<<<dim3((Vv + 255) / 256, Bsz), 256, 0, stream>>>(out, lse);
}

// Round 2
// 439.831 us; speedup vs baseline: 2.1362x; 2.1362x over previous
//
#include <hip/hip_runtime.h>
#include <hip/hip_bf16.h>
#include <math.h>

constexpr int Bsz = 64, Cctx = 200, Hdim = 1024, Vv = 50257;
constexpr float NEG_INF_V = -100000.0f;

typedef __attribute__((ext_vector_type(8))) short s16x8;
typedef __attribute__((ext_vector_type(4))) short s16x4;
typedef __attribute__((ext_vector_type(4))) float fx4;

__device__ __forceinline__ unsigned short f2bf(float f) {
  unsigned int u = __builtin_bit_cast(unsigned int, f);
  unsigned int r = (u + 0x7fffu + ((u >> 16) & 1u)) >> 16;
  return (unsigned short)r;
}

// ---------------- skinny streaming GEMM: C(64,N) = A(64,K)bf16 @ B(N,K)f32^T ----
// One wave per 16 rows of B; no LDS, no barriers. EPI 0: store. 2: store+bias.
template<int EPI>
__global__ __launch_bounds__(256)
void stream_gemm(const unsigned short* __restrict__ Ab,
                 const float* __restrict__ Bm, int N, int K,
                 const float* __restrict__ bias, float* __restrict__ Cout) {
  const int lane = threadIdx.x & 63;
  const int wid = threadIdx.x >> 6;
  const int n0 = (blockIdx.x * 4 + wid) * 16;
  if (n0 >= N) return;
  const int c = lane & 15;
  const int q = lane >> 4;
  const int brow = min(n0 + c, N - 1);
  const float* bp = Bm + (size_t)brow * K + q * 8;
  const unsigned short* ap = Ab + (size_t)c * K + q * 8;

  fx4 acc[4] = {};
  float4 b0 = *reinterpret_cast<const float4*>(bp);
  float4 b1 = *reinterpret_cast<const float4*>(bp + 4);
  for (int kt = 0; kt < K; kt += 32) {
    float4 c0 = b0, c1 = b1;
    if (kt + 32 < K) {
      b0 = *reinterpret_cast<const float4*>(bp + kt + 32);
      b1 = *reinterpret_cast<const float4*>(bp + kt + 36);
    }
    s16x8 bf;
    bf[0] = (short)f2bf(c0.x); bf[1] = (short)f2bf(c0.y);
    bf[2] = (short)f2bf(c0.z); bf[3] = (short)f2bf(c0.w);
    bf[4] = (short)f2bf(c1.x); bf[5] = (short)f2bf(c1.y);
    bf[6] = (short)f2bf(c1.z); bf[7] = (short)f2bf(c1.w);
    #pragma unroll
    for (int i = 0; i < 4; ++i) {
      s16x8 af = *reinterpret_cast<const s16x8*>(ap + (size_t)i * 16 * K + kt);
      acc[i] = __builtin_amdgcn_mfma_f32_16x16x32_bf16(af, bf, acc[i], 0, 0, 0);
    }
  }
  const int n = n0 + c;
  if (n < N) {
    float bv = (EPI == 2) ? bias[n] : 0.f;
    #pragma unroll
    for (int i = 0; i < 4; ++i)
      #pragma unroll
      for (int p = 0; p < 4; ++p)
        Cout[(size_t)(i * 16 + q * 4 + p) * N + n] = acc[i][p] + bv;
  }
}

// ---------------- attention GEMM: bf16 A(12800,1024) @ B(1024,1024)^T, fused tanh.v ----
__global__ __launch_bounds__(256)
void gemm_att(const unsigned short* __restrict__ Ab, const unsigned short* __restrict__ Bb,
              const float* __restrict__ qmat, const float* __restrict__ vvec,
              float* __restrict__ scores) {
  constexpr int BM = 128, BN = 128, BK = 64, LDT = BK + 8;
  __shared__ unsigned short As[BM * LDT];
  __shared__ unsigned short Bs[BN * LDT];
  const int tid = threadIdx.x, lane = tid & 63, wid = tid >> 6;
  const int wm0 = (wid >> 1) * 64, wn0 = (wid & 1) * 64;
  const int bm0 = blockIdx.y * BM, bn0 = blockIdx.x * BN;
  const int ar = lane & 15, ak = (lane >> 4) * 8;
  fx4 acc[4][4] = {};

  for (int kt = 0; kt < Hdim; kt += BK) {
    #pragma unroll
    for (int j = 0; j < 4; ++j) {           // A: 1024 16B-segs / 256 thr
      int s = tid + j * 256, row = s >> 3, seg = s & 7;
      *reinterpret_cast<s16x8*>(&As[row * LDT + seg * 8]) =
          *reinterpret_cast<const s16x8*>(&Ab[(size_t)(bm0 + row) * Hdim + kt + seg * 8]);
    }
    #pragma unroll
    for (int j = 0; j < 4; ++j) {
      int s = tid + j * 256, row = s >> 3, seg = s & 7;
      *reinterpret_cast<s16x8*>(&Bs[row * LDT + seg * 8]) =
          *reinterpret_cast<const s16x8*>(&Bb[(size_t)(bn0 + row) * Hdim + kt + seg * 8]);
    }
    __syncthreads();
    #pragma unroll
    for (int kk = 0; kk < 2; ++kk) {
      s16x8 a[4], b[4];
      #pragma unroll
      for (int i = 0; i < 4; ++i)
        a[i] = *reinterpret_cast<const s16x8*>(&As[(wm0 + i * 16 + ar) * LDT + kk * 32 + ak]);
      #pragma unroll
      for (int j = 0; j < 4; ++j)
        b[j] = *reinterpret_cast<const s16x8*>(&Bs[(wn0 + j * 16 + ar) * LDT + kk * 32 + ak]);
      #pragma unroll
      for (int i = 0; i < 4; ++i)
        #pragma unroll
        for (int j = 0; j < 4; ++j)
          acc[i][j] = __builtin_amdgcn_mfma_f32_16x16x32_bf16(a[i], b[j], acc[i][j], 0, 0, 0);
    }
    __syncthreads();
  }

  const int rg = (lane >> 4) * 4, cg = lane & 15;
  #pragma unroll
  for (int i = 0; i < 4; ++i) {
    #pragma unroll
    for (int p = 0; p < 4; ++p) {
      int mg = bm0 + wm0 + i * 16 + rg + p;
      int brow = mg & 63;
      float rs = 0.f;
      #pragma unroll
      for (int j = 0; j < 4; ++j) {
        int ng = bn0 + wn0 + j * 16 + cg;
        float t = tanhf(acc[i][j][p] + qmat[brow * Hdim + ng]);
        rs += t * vvec[ng];
      }
      rs += __shfl_xor(rs, 1); rs += __shfl_xor(rs, 2);
      rs += __shfl_xor(rs, 4); rs += __shfl_xor(rs, 8);
      if (cg == 0) atomicAdd(&scores[brow * Cctx + (mg >> 6)], rs);
    }
  }
}

// ---------------- small helpers ----------------
__global__ void transpose1024(const float* __restrict__ in, float* __restrict__ out) {
  __shared__ float t[32][33];
  int tx = threadIdx.x, ty = threadIdx.y;
  int bx = blockIdx.x * 32, by = blockIdx.y * 32;
  #pragma unroll
  for (int r = 0; r < 32; r += 8) t[ty + r][tx] = in[(size_t)(by + ty + r) * 1024 + bx + tx];
  __syncthreads();
  #pragma unroll
  for (int r = 0; r < 32; r += 8) out[(size_t)(bx + ty + r) * 1024 + by + tx] = t[tx][ty + r];
}

__global__ void transpose_conv(const float* __restrict__ in, unsigned short* __restrict__ out) {
  __shared__ float t[32][33];
  int tx = threadIdx.x, ty = threadIdx.y;
  int bx = blockIdx.x * 32, by = blockIdx.y * 32;
  #pragma unroll
  for (int r = 0; r < 32; r += 8) t[ty + r][tx] = in[(size_t)(by + ty + r) * 1024 + bx + tx];
  __syncthreads();
  #pragma unroll
  for (int r = 0; r < 32; r += 8) out[(size_t)(bx + ty + r) * 1024 + by + tx] = f2bf(t[tx][ty + r]);
}

__global__ void conv_bf16(const float* __restrict__ in, unsigned short* __restrict__ out) {
  size_t i = (size_t)(blockIdx.x * 256 + threadIdx.x) * 8;
  float4 a = *reinterpret_cast<const float4*>(in + i);
  float4 b = *reinterpret_cast<const float4*>(in + i + 4);
  s16x8 h;
  h[0] = (short)f2bf(a.x); h[1] = (short)f2bf(a.y); h[2] = (short)f2bf(a.z); h[3] = (short)f2bf(a.w);
  h[4] = (short)f2bf(b.x); h[5] = (short)f2bf(b.y); h[6] = (short)f2bf(b.z); h[7] = (short)f2bf(b.w);
  *reinterpret_cast<s16x8*>(out + i) = h;
}

__global__ __launch_bounds__(256)
void softmax_pad(const float* __restrict__ scores, const int* __restrict__ pad,
                 float* __restrict__ attn) {
  int b = blockIdx.x, t = threadIdx.x;
  int lane = t & 63, wid = t >> 6;
  __shared__ float red[8];
  float sv = 0.f, v = -3.4e38f;
  if (t < Cctx) { sv = pad[b * Cctx + t] ? NEG_INF_V : scores[b * Cctx + t]; v = sv; }
  #pragma unroll
  for (int o = 1; o < 64; o <<= 1) v = fmaxf(v, __shfl_xor(v, o));
  if (lane == 0) red[wid] = v;
  __syncthreads();
  float m = fmaxf(fmaxf(red[0], red[1]), fmaxf(red[2], red[3]));
  float e = (t < Cctx) ? expf(sv - m) : 0.f;
  float s = e;
  #pragma unroll
  for (int o = 1; o < 64; o <<= 1) s += __shfl_xor(s, o);
  if (lane == 0) red[4 + wid] = s;
  __syncthreads();
  float tot = red[4] + red[5] + red[6] + red[7];
  if (t < Cctx) attn[b * Cctx + t] = e / tot;
}

// applied partial sums: part[b][g][h] = sum_{c in group g} attn[b][c]*ch[b][c][h]
__global__ __launch_bounds__(256)
void applied_part(const float* __restrict__ attn, const float* __restrict__ ch,
                  float* __restrict__ part) {
  int g = blockIdx.x, b = blockIdx.y;
  int h = threadIdx.x * 4;
  float4 acc = make_float4(0.f, 0.f, 0.f, 0.f);
  for (int c = g * 25; c < g * 25 + 25; ++c) {
    float a = attn[b * Cctx + c];
    float4 v = *reinterpret_cast<const float4*>(&ch[((size_t)b * Cctx + c) * Hdim + h]);
    acc.x += a * v.x; acc.y += a * v.y; acc.z += a * v.z; acc.w += a * v.w;
  }
  *reinterpret_cast<float4*>(&part[((size_t)b * 8 + g) * Hdim + h]) = acc;
}

__global__ void build_xb(const float* __restrict__ inp, const float* __restrict__ topic,
                         const float* __restrict__ part, unsigned short* __restrict__ xb) {
  int j = blockIdx.x * 256 + threadIdx.x;   // 0..3071
  int b = blockIdx.y;
  float v;
  if (j < 1024) v = inp[b * 1024 + j];
  else if (j < 2048) v = topic[b * 1024 + (j - 1024)];
  else {
    const float* pp = &part[(size_t)b * 8 * Hdim + (j - 2048)];
    v = 0.f;
    #pragma unroll
    for (int g = 0; g < 8; ++g) v += pp[g * Hdim];
  }
  xb[(size_t)b * 3072 + j] = f2bf(v);
}

__global__ void gru_gate(const float* __restrict__ gi, const float* __restrict__ gh,
                         const float* __restrict__ h0, float* __restrict__ out_h,
                         unsigned short* __restrict__ hnb) {
  int idx = blockIdx.x * blockDim.x + threadIdx.x;   // B*H
  int b = idx >> 10, j = idx & 1023;
  const float* gib = gi + (size_t)b * 3072;
  const float* ghb = gh + (size_t)b * 3072;
  float r = 1.f / (1.f + expf(-(gib[j] + ghb[j])));
  float z = 1.f / (1.f + expf(-(gib[1024 + j] + ghb[1024 + j])));
  float n = tanhf(gib[2048 + j] + r * ghb[2048 + j]);
  float h = (1.f - z) * n + z * h0[idx];
  out_h[idx] = h;
  hnb[idx] = f2bf(h);
}

__global__ __launch_bounds__(256)
void row_lse(const float* __restrict__ logits, float* __restrict__ lse) {
  int b = blockIdx.x, t = threadIdx.x;
  int lane = t & 63, wid = t >> 6;
  __shared__ float red[8];
  const float* row = logits + (size_t)b * Vv;
  float m = -3.4e38f;
  for (int i = t; i < Vv; i += 256) m = fmaxf(m, row[i]);
  #pragma unroll
  for (int o = 1; o < 64; o <<= 1) m = fmaxf(m, __shfl_xor(m, o));
  if (lane == 0) red[wid] = m;
  __syncthreads();
  m = fmaxf(fmaxf(red[0], red[1]), fmaxf(red[2], red[3]));
  float s = 0.f;
  for (int i = t; i < Vv; i += 256) s += expf(row[i] - m);
  #pragma unroll
  for (int o = 1; o < 64; o <<= 1) s += __shfl_xor(s, o);
  if (lane == 0) red[4 + wid] = s;
  __syncthreads();
  if (t == 0) lse[b] = m + logf(red[4] + red[5] + red[6] + red[7]);
}

__global__ void sub_lse(float* __restrict__ out, const float* __restrict__ lse) {
  int b = blockIdx.y;
  int i = blockIdx.x * 256 + threadIdx.x;
  if (i < Vv) out[(size_t)b * Vv + i] -= lse[b];
}

extern "C" void kernel_launch(void* const* d_in, const int* in_sizes, int n_in,
                              void* d_out, int out_size, void* d_ws, size_t ws_size,
                              hipStream_t stream) {
  const float* input  = (const float*)d_in[0];
  const float* hidden = (const float*)d_in[1];
  const float* lch    = (const float*)d_in[2];
  const float* ch     = (const float*)d_in[3];
  const float* topic  = (const float*)d_in[4];
  const int*   pad    = (const int*)d_in[5];
  const float* dyna_W = (const float*)d_in[6];
  const float* dyna_U = (const float*)d_in[7];
  const float* dyna_v = (const float*)d_in[8];
  const float* W_ih   = (const float*)d_in[9];
  const float* W_hh   = (const float*)d_in[10];
  const float* b_ih   = (const float*)d_in[11];
  const float* b_hh   = (const float*)d_in[12];
  const float* W_out  = (const float*)d_in[13];
  const float* b_out  = (const float*)d_in[14];

  float* out   = (float*)d_out;
  float* out_h = out + (size_t)Bsz * Vv;

  float* p = (float*)d_ws;
  float* Wt     = p; p += 1024 * 1024;
  float* q      = p; p += Bsz * Hdim;
  float* scores = p; p += Bsz * Cctx;
  float* attn   = p; p += Bsz * Cctx;
  float* part   = p; p += Bsz * 8 * Hdim;
  float* gi     = p; p += Bsz * 3072;
  float* gh     = p; p += Bsz * 3072;
  float* lse    = p; p += 64;
  unsigned short* up = (unsigned short*)p;
  unsigned short* ub  = up; up += 1024 * 1024;
  unsigned short* lb  = up; up += (size_t)Cctx * Bsz * Hdim;
  unsigned short* h0b = up; up += Bsz * Hdim;
  unsigned short* hnb = up; up += Bsz * Hdim;
  unsigned short* xb  = up; up += Bsz * 3072;

  dim3 tt(32, 8);
  transpose1024<<<dim3(32, 32), tt, 0, stream>>>(dyna_W, Wt);
  transpose_conv<<<dim3(32, 32), tt, 0, stream>>>(dyna_U, ub);
  conv_bf16<<<(Cctx * Bsz * Hdim) / 2048, 256, 0, stream>>>(lch, lb);
  conv_bf16<<<(Bsz * Hdim) / 2048, 256, 0, stream>>>(hidden, h0b);
  hipMemsetAsync(scores, 0, Bsz * Cctx * sizeof(float), stream);

  // q = h0 @ dyna_W  (N=1024, K=1024)
  stream_gemm<0><<<16, 256, 0, stream>>>(h0b, Wt, Hdim, Hdim, nullptr, q);

  // scores += tanh(q + lch@U) . v
  gemm_att<<<dim3(8, 100), 256, 0, stream>>>(lb, ub, q, dyna_v, scores);

  softmax_pad<<<Bsz, 256, 0, stream>>>(scores, pad, attn);
  applied_part<<<dim3(8, Bsz), 256, 0, stream>>>(attn, ch, part);
  build_xb<<<dim3(12, Bsz), 256, 0, stream>>>(input, topic, part, xb);

  // gi = x @ W_ih^T + b_ih  (N=3072, K=3072)
  stream_gemm<2><<<48, 256, 0, stream>>>(xb, W_ih, 3072, 3072, b_ih, gi);
  // gh = h0 @ W_hh^T + b_hh (N=3072, K=1024)
  stream_gemm<2><<<48, 256, 0, stream>>>(h0b, W_hh, 3072, Hdim, b_hh, gh);

  gru_gate<<<(Bsz * Hdim) / 256, 256, 0, stream>>>(gi, gh, hidden, out_h, hnb);

  // logits = h_new @ W_out^T + b_out  (N=50257, K=1024)
  stream_gemm<2><<<(Vv / 16 + 4) / 4, 256, 0, stream>>>(hnb, W_out, Vv, Hdim, b_out, out);

  row_lse<<<Bsz, 256, 0, stream>>>(out, lse);
  sub_lse<<<dim3((Vv + 255) / 256, Bsz), 256, 0, stream>>>(out, lse);
}

// Round 3
// 277.861 us; speedup vs baseline: 3.3814x; 1.5829x over previous
//
#include <hip/hip_runtime.h>
#include <hip/hip_bf16.h>
#include <math.h>

constexpr int Bsz = 64, Cctx = 200, Hdim = 1024, Vv = 50257;
constexpr float NEG_INF_V = -100000.0f;

typedef __attribute__((ext_vector_type(8))) short s16x8;
typedef __attribute__((ext_vector_type(4))) float fx4;
typedef unsigned int u32;

__device__ __forceinline__ unsigned short f2bf(float f) {
  unsigned int u = __builtin_bit_cast(unsigned int, f);
  unsigned int r = (u + 0x7fffu + ((u >> 16) & 1u)) >> 16;
  return (unsigned short)r;
}

__device__ __forceinline__ void gl_lds16(const unsigned short* g, unsigned short* l) {
  __builtin_amdgcn_global_load_lds(
      (const __attribute__((address_space(1))) u32*)g,
      (__attribute__((address_space(3))) u32*)l, 16, 0, 0);
}

// ---------- attention GEMM, m97 structure: global_load_lds + linear LDS ----------
// A(12800,1024)bf16 @ B(1024,1024)bf16^T, fused tanh(.+q).v epilogue -> scores atomics
__global__ __launch_bounds__(256)
void gemm_att(const unsigned short* __restrict__ Ab, const unsigned short* __restrict__ Bb,
              const float* __restrict__ qmat, const float* __restrict__ vvec,
              float* __restrict__ scores) {
  __shared__ unsigned short As[128 * 64];
  __shared__ unsigned short Bs[128 * 64];
  // XCD-grouping remap: grid (8,104) flat; xcd = f&7 owns 13 M-tiles x 8 N-tiles
  int f = blockIdx.x + blockIdx.y * 8;
  int xcd = f & 7, j = f >> 3;
  int my = xcd + 8 * (j % 13), mx = j / 13;
  if (my >= 100) return;
  const int bm0 = my * 128, bn0 = mx * 128;
  const int tid = threadIdx.x, lane = tid & 63, wid = tid >> 6;
  const int wm0 = (wid >> 1) * 64, wn0 = (wid & 1) * 64;
  const int ar = lane & 15, ak = (lane >> 4) * 8;
  fx4 acc[4][4] = {};

  for (int kt = 0; kt < Hdim; kt += 64) {
    #pragma unroll
    for (int i = 0; i < 4; ++i) {
      int s = tid + i * 256;
      int row = s >> 3, seg = s & 7;
      gl_lds16(&Ab[(size_t)(bm0 + row) * Hdim + kt + seg * 8], &As[s * 8]);
    }
    #pragma unroll
    for (int i = 0; i < 4; ++i) {
      int s = tid + i * 256;
      int row = s >> 3, seg = s & 7;
      gl_lds16(&Bb[(size_t)(bn0 + row) * Hdim + kt + seg * 8], &Bs[s * 8]);
    }
    __syncthreads();
    #pragma unroll
    for (int kk = 0; kk < 2; ++kk) {
      s16x8 a[4], b[4];
      #pragma unroll
      for (int i = 0; i < 4; ++i)
        a[i] = *reinterpret_cast<const s16x8*>(&As[(wm0 + i * 16 + ar) * 64 + kk * 32 + ak]);
      #pragma unroll
      for (int j2 = 0; j2 < 4; ++j2)
        b[j2] = *reinterpret_cast<const s16x8*>(&Bs[(wn0 + j2 * 16 + ar) * 64 + kk * 32 + ak]);
      #pragma unroll
      for (int i = 0; i < 4; ++i)
        #pragma unroll
        for (int j2 = 0; j2 < 4; ++j2)
          acc[i][j2] = __builtin_amdgcn_mfma_f32_16x16x32_bf16(a[i], b[j2], acc[i][j2], 0, 0, 0);
    }
    __syncthreads();
  }

  const int rg = (lane >> 4) * 4, cg = lane & 15;
  #pragma unroll
  for (int i = 0; i < 4; ++i) {
    #pragma unroll
    for (int p = 0; p < 4; ++p) {
      int mg = bm0 + wm0 + i * 16 + rg + p;
      int brow = mg & 63;
      float rs = 0.f;
      #pragma unroll
      for (int j2 = 0; j2 < 4; ++j2) {
        int ng = bn0 + wn0 + j2 * 16 + cg;
        float t = tanhf(acc[i][j2][p] + qmat[brow * Hdim + ng]);
        rs += t * vvec[ng];
      }
      rs += __shfl_xor(rs, 1); rs += __shfl_xor(rs, 2);
      rs += __shfl_xor(rs, 4); rs += __shfl_xor(rs, 8);
      if (cg == 0) atomicAdd(&scores[brow * Cctx + (mg >> 6)], rs);
    }
  }
}

// ---------- 1-wave streaming GEMM body: C(64,Ncols) = A(64,K)bf16 @ B(.,K)f32^T ----
__device__ __forceinline__ void stream_body(const unsigned short* ap, const float* bp,
                                            int K, fx4 acc[4]) {
  float4 b0 = *reinterpret_cast<const float4*>(bp);
  float4 b1 = *reinterpret_cast<const float4*>(bp + 4);
  float4 b2 = *reinterpret_cast<const float4*>(bp + 32);
  float4 b3 = *reinterpret_cast<const float4*>(bp + 36);
  for (int kt = 0; kt < K; kt += 64) {
    float4 c0 = b0, c1 = b1, c2 = b2, c3 = b3;
    if (kt + 64 < K) {
      b0 = *reinterpret_cast<const float4*>(bp + kt + 64);
      b1 = *reinterpret_cast<const float4*>(bp + kt + 68);
      b2 = *reinterpret_cast<const float4*>(bp + kt + 96);
      b3 = *reinterpret_cast<const float4*>(bp + kt + 100);
    }
    s16x8 bf0, bf1;
    bf0[0] = (short)f2bf(c0.x); bf0[1] = (short)f2bf(c0.y);
    bf0[2] = (short)f2bf(c0.z); bf0[3] = (short)f2bf(c0.w);
    bf0[4] = (short)f2bf(c1.x); bf0[5] = (short)f2bf(c1.y);
    bf0[6] = (short)f2bf(c1.z); bf0[7] = (short)f2bf(c1.w);
    bf1[0] = (short)f2bf(c2.x); bf1[1] = (short)f2bf(c2.y);
    bf1[2] = (short)f2bf(c2.z); bf1[3] = (short)f2bf(c2.w);
    bf1[4] = (short)f2bf(c3.x); bf1[5] = (short)f2bf(c3.y);
    bf1[6] = (short)f2bf(c3.z); bf1[7] = (short)f2bf(c3.w);
    #pragma unroll
    for (int i = 0; i < 4; ++i) {
      s16x8 af = *reinterpret_cast<const s16x8*>(ap + (size_t)i * 16 * K + kt);
      acc[i] = __builtin_amdgcn_mfma_f32_16x16x32_bf16(af, bf0, acc[i], 0, 0, 0);
    }
    #pragma unroll
    for (int i = 0; i < 4; ++i) {
      s16x8 af = *reinterpret_cast<const s16x8*>(ap + (size_t)i * 16 * K + kt + 32);
      acc[i] = __builtin_amdgcn_mfma_f32_16x16x32_bf16(af, bf1, acc[i], 0, 0, 0);
    }
  }
}

template<int EPI>  // 0: plain, 2: +bias
__global__ __launch_bounds__(64)
void stream_gemm(const unsigned short* __restrict__ Ab,
                 const float* __restrict__ Bm, int N, int K,
                 const float* __restrict__ bias, float* __restrict__ Cout) {
  const int lane = threadIdx.x;
  const int n0 = blockIdx.x * 16;
  const int c = lane & 15, qq = lane >> 4;
  const int brow = min(n0 + c, N - 1);
  fx4 acc[4] = {};
  stream_body(Ab + (size_t)c * K + qq * 8, Bm + (size_t)brow * K + qq * 8, K, acc);
  const int n = n0 + c;
  if (n < N) {
    float bv = (EPI == 2) ? bias[n] : 0.f;
    #pragma unroll
    for (int i = 0; i < 4; ++i)
      #pragma unroll
      for (int p = 0; p < 4; ++p)
        Cout[(size_t)(i * 16 + qq * 4 + p) * N + n] = acc[i][p] + bv;
  }
}

// q = h0@Wt (N=1024) and gh = h0@W_hh^T + b_hh (N=3072), one wave per 16 cols
__global__ __launch_bounds__(64)
void qgh_gemm(const unsigned short* __restrict__ h0b, const float* __restrict__ Wt,
              const float* __restrict__ Whh, const float* __restrict__ bhh,
              float* __restrict__ q, float* __restrict__ gh) {
  const int lane = threadIdx.x;
  const int gw = blockIdx.x;            // 0..255
  const bool isq = gw < 64;
  const int n0 = isq ? gw * 16 : (gw - 64) * 16;
  const int N = isq ? 1024 : 3072;
  const float* B = isq ? Wt : Whh;
  const int c = lane & 15, qq = lane >> 4;
  fx4 acc[4] = {};
  stream_body(h0b + (size_t)c * 1024 + qq * 8, B + (size_t)(n0 + c) * 1024 + qq * 8, 1024, acc);
  const int n = n0 + c;
  float bv = isq ? 0.f : bhh[n];
  float* C = isq ? q : gh;
  #pragma unroll
  for (int i = 0; i < 4; ++i)
    #pragma unroll
    for (int p = 0; p < 4; ++p)
      C[(size_t)(i * 16 + qq * 4 + p) * N + n] = acc[i][p] + bv;
}

// gi partials, K split in 4 chunks of 768: part[w][64][3072]
__global__ __launch_bounds__(64)
void gi_split(const unsigned short* __restrict__ xb, const float* __restrict__ Wih,
              float* __restrict__ part) {
  const int lane = threadIdx.x;
  const int t = blockIdx.x;             // n-tile 0..191
  const int w = blockIdx.y;             // k-chunk 0..3
  const int c = lane & 15, qq = lane >> 4;
  constexpr int K = 3072, CH = 768;
  const float* bp = Wih + (size_t)(t * 16 + c) * K + w * CH + qq * 8;
  const unsigned short* ap = xb + (size_t)c * K + w * CH + qq * 8;
  fx4 acc[4] = {};
  float4 b0 = *reinterpret_cast<const float4*>(bp);
  float4 b1 = *reinterpret_cast<const float4*>(bp + 4);
  float4 b2 = *reinterpret_cast<const float4*>(bp + 32);
  float4 b3 = *reinterpret_cast<const float4*>(bp + 36);
  for (int kt = 0; kt < CH; kt += 64) {
    float4 c0 = b0, c1 = b1, c2 = b2, c3 = b3;
    if (kt + 64 < CH) {
      b0 = *reinterpret_cast<const float4*>(bp + kt + 64);
      b1 = *reinterpret_cast<const float4*>(bp + kt + 68);
      b2 = *reinterpret_cast<const float4*>(bp + kt + 96);
      b3 = *reinterpret_cast<const float4*>(bp + kt + 100);
    }
    s16x8 bf0, bf1;
    bf0[0] = (short)f2bf(c0.x); bf0[1] = (short)f2bf(c0.y);
    bf0[2] = (short)f2bf(c0.z); bf0[3] = (short)f2bf(c0.w);
    bf0[4] = (short)f2bf(c1.x); bf0[5] = (short)f2bf(c1.y);
    bf0[6] = (short)f2bf(c1.z); bf0[7] = (short)f2bf(c1.w);
    bf1[0] = (short)f2bf(c2.x); bf1[1] = (short)f2bf(c2.y);
    bf1[2] = (short)f2bf(c2.z); bf1[3] = (short)f2bf(c2.w);
    bf1[4] = (short)f2bf(c3.x); bf1[5] = (short)f2bf(c3.y);
    bf1[6] = (short)f2bf(c3.z); bf1[7] = (short)f2bf(c3.w);
    #pragma unroll
    for (int i = 0; i < 4; ++i) {
      s16x8 af = *reinterpret_cast<const s16x8*>(ap + (size_t)i * 16 * K + kt);
      acc[i] = __builtin_amdgcn_mfma_f32_16x16x32_bf16(af, bf0, acc[i], 0, 0, 0);
    }
    #pragma unroll
    for (int i = 0; i < 4; ++i) {
      s16x8 af = *reinterpret_cast<const s16x8*>(ap + (size_t)i * 16 * K + kt + 32);
      acc[i] = __builtin_amdgcn_mfma_f32_16x16x32_bf16(af, bf1, acc[i], 0, 0, 0);
    }
  }
  float* po = part + (size_t)w * 64 * 3072;
  const int n = t * 16 + c;
  #pragma unroll
  for (int i = 0; i < 4; ++i)
    #pragma unroll
    for (int p = 0; p < 4; ++p)
      po[(size_t)(i * 16 + qq * 4 + p) * 3072 + n] = acc[i][p];
}

// ---------- prep: W transpose (f32), U transpose (bf16), h0 conv ----------
__global__ __launch_bounds__(256)
void prep(const float* __restrict__ dW, const float* __restrict__ dU,
          const float* __restrict__ h0, float* __restrict__ Wt,
          unsigned short* __restrict__ ub, unsigned short* __restrict__ h0b) {
  const int z = blockIdx.z;
  const int tx = threadIdx.x & 31, ty = threadIdx.x >> 5;   // 32x8
  if (z < 2) {
    __shared__ float t[32][33];
    const float* in = z ? dU : dW;
    int bx = blockIdx.x * 32, by = blockIdx.y * 32;
    #pragma unroll
    for (int r = 0; r < 32; r += 8) t[ty + r][tx] = in[(size_t)(by + ty + r) * 1024 + bx + tx];
    __syncthreads();
    if (z == 0) {
      #pragma unroll
      for (int r = 0; r < 32; r += 8) Wt[(size_t)(bx + ty + r) * 1024 + by + tx] = t[tx][ty + r];
    } else {
      #pragma unroll
      for (int r = 0; r < 32; r += 8) ub[(size_t)(bx + ty + r) * 1024 + by + tx] = f2bf(t[tx][ty + r]);
    }
  } else {
    if (blockIdx.y) return;
    size_t i = (size_t)(blockIdx.x * 256 + threadIdx.x) * 8;   // 64*1024 total
    float4 a = *reinterpret_cast<const float4*>(h0 + i);
    float4 b = *reinterpret_cast<const float4*>(h0 + i + 4);
    s16x8 h;
    h[0] = (short)f2bf(a.x); h[1] = (short)f2bf(a.y); h[2] = (short)f2bf(a.z); h[3] = (short)f2bf(a.w);
    h[4] = (short)f2bf(b.x); h[5] = (short)f2bf(b.y); h[6] = (short)f2bf(b.z); h[7] = (short)f2bf(b.w);
    *reinterpret_cast<s16x8*>(h0b + i) = h;
  }
}

__global__ void conv_bf16(const float* __restrict__ in, unsigned short* __restrict__ out) {
  size_t i = (size_t)(blockIdx.x * 256 + threadIdx.x) * 8;
  float4 a = *reinterpret_cast<const float4*>(in + i);
  float4 b = *reinterpret_cast<const float4*>(in + i + 4);
  s16x8 h;
  h[0] = (short)f2bf(a.x); h[1] = (short)f2bf(a.y); h[2] = (short)f2bf(a.z); h[3] = (short)f2bf(a.w);
  h[4] = (short)f2bf(b.x); h[5] = (short)f2bf(b.y); h[6] = (short)f2bf(b.z); h[7] = (short)f2bf(b.w);
  *reinterpret_cast<s16x8*>(out + i) = h;
}

// ---------- softmax (redundant per g) + applied partial ----------
__global__ __launch_bounds__(256)
void softmax_applied(const float* __restrict__ scores, const int* __restrict__ pad,
                     const float* __restrict__ ch, float* __restrict__ part) {
  const int g = blockIdx.x, b = blockIdx.y, t = threadIdx.x;
  const int lane = t & 63, w = t >> 6;
  __shared__ float at[256];
  __shared__ float red[8];
  float sv = 0.f, v = -3.4e38f;
  if (t < Cctx) { sv = pad[b * Cctx + t] ? NEG_INF_V : scores[b * Cctx + t]; v = sv; }
  #pragma unroll
  for (int o = 1; o < 64; o <<= 1) v = fmaxf(v, __shfl_xor(v, o));
  if (lane == 0) red[w] = v;
  __syncthreads();
  float m = fmaxf(fmaxf(red[0], red[1]), fmaxf(red[2], red[3]));
  float e = (t < Cctx) ? expf(sv - m) : 0.f;
  float s = e;
  #pragma unroll
  for (int o = 1; o < 64; o <<= 1) s += __shfl_xor(s, o);
  if (lane == 0) red[4 + w] = s;
  __syncthreads();
  float tot = red[4] + red[5] + red[6] + red[7];
  at[t] = e / tot;
  __syncthreads();
  const int h = t * 4;
  float4 a4 = make_float4(0.f, 0.f, 0.f, 0.f);
  for (int c2 = g * 25; c2 < g * 25 + 25; ++c2) {
    float a = at[c2];
    float4 vv = *reinterpret_cast<const float4*>(&ch[((size_t)b * Cctx + c2) * Hdim + h]);
    a4.x += a * vv.x; a4.y += a * vv.y; a4.z += a * vv.z; a4.w += a * vv.w;
  }
  *reinterpret_cast<float4*>(&part[((size_t)b * 8 + g) * Hdim + h]) = a4;
}

__global__ void build_xb(const float* __restrict__ inp, const float* __restrict__ topic,
                         const float* __restrict__ part, unsigned short* __restrict__ xb) {
  int j = blockIdx.x * 256 + threadIdx.x;
  int b = blockIdx.y;
  float v;
  if (j < 1024) v = inp[b * 1024 + j];
  else if (j < 2048) v = topic[b * 1024 + (j - 1024)];
  else {
    const float* pp = &part[(size_t)b * 8 * Hdim + (j - 2048)];
    v = 0.f;
    #pragma unroll
    for (int g = 0; g < 8; ++g) v += pp[g * Hdim];
  }
  xb[(size_t)b * 3072 + j] = f2bf(v);
}

__global__ void gru_gate(const float* __restrict__ pgi, const float* __restrict__ bih,
                         const float* __restrict__ gh, const float* __restrict__ h0,
                         float* __restrict__ out_h, unsigned short* __restrict__ hnb) {
  int idx = blockIdx.x * 256 + threadIdx.x;
  int b = idx >> 10, j = idx & 1023;
  float gr = bih[j], gz = bih[1024 + j], gn = bih[2048 + j];
  const float* pb = pgi + (size_t)b * 3072;
  #pragma unroll
  for (int w = 0; w < 4; ++w) {
    const float* pw = pb + (size_t)w * 64 * 3072;
    gr += pw[j]; gz += pw[1024 + j]; gn += pw[2048 + j];
  }
  const float* ghb = gh + (size_t)b * 3072;
  float r = 1.f / (1.f + expf(-(gr + ghb[j])));
  float z = 1.f / (1.f + expf(-(gz + ghb[1024 + j])));
  float n = tanhf(gn + r * ghb[2048 + j]);
  float h = (1.f - z) * n + z * h0[idx];
  out_h[idx] = h;
  hnb[idx] = f2bf(h);
}

// ---------- fused log-softmax: max, sum, subtract (passes 2-3 are L2-hot) ----------
__global__ __launch_bounds__(1024)
void lse_fused(float* __restrict__ out) {
  const int b = blockIdx.x, t = threadIdx.x, lane = t & 63, w = t >> 6;
  __shared__ float red[16];
  float* row = out + (size_t)b * Vv;
  float m = -3.4e38f;
  for (int i = t; i < Vv; i += 1024) m = fmaxf(m, row[i]);
  #pragma unroll
  for (int o = 1; o < 64; o <<= 1) m = fmaxf(m, __shfl_xor(m, o));
  if (lane == 0) red[w] = m;
  __syncthreads();
  float mm = red[0];
  #pragma unroll
  for (int k = 1; k < 16; ++k) mm = fmaxf(mm, red[k]);
  float s = 0.f;
  for (int i = t; i < Vv; i += 1024) s += expf(row[i] - mm);
  #pragma unroll
  for (int o = 1; o < 64; o <<= 1) s += __shfl_xor(s, o);
  __syncthreads();
  if (lane == 0) red[w] = s;
  __syncthreads();
  float ss = 0.f;
  #pragma unroll
  for (int k = 0; k < 16; ++k) ss += red[k];
  float lse = mm + logf(ss);
  for (int i = t; i < Vv; i += 1024) row[i] -= lse;
}

extern "C" void kernel_launch(void* const* d_in, const int* in_sizes, int n_in,
                              void* d_out, int out_size, void* d_ws, size_t ws_size,
                              hipStream_t stream) {
  const float* input  = (const float*)d_in[0];
  const float* hidden = (const float*)d_in[1];
  const float* lch    = (const float*)d_in[2];
  const float* ch     = (const float*)d_in[3];
  const float* topic  = (const float*)d_in[4];
  const int*   pad    = (const int*)d_in[5];
  const float* dyna_W = (const float*)d_in[6];
  const float* dyna_U = (const float*)d_in[7];
  const float* dyna_v = (const float*)d_in[8];
  const float* W_ih   = (const float*)d_in[9];
  const float* W_hh   = (const float*)d_in[10];
  const float* b_ih   = (const float*)d_in[11];
  const float* b_hh   = (const float*)d_in[12];
  const float* W_out  = (const float*)d_in[13];
  const float* b_out  = (const float*)d_in[14];

  float* out   = (float*)d_out;
  float* out_h = out + (size_t)Bsz * Vv;

  float* p = (float*)d_ws;
  float* Wt      = p; p += 1024 * 1024;
  float* q       = p; p += Bsz * Hdim;
  float* scores  = p; p += Bsz * Cctx;
  float* part_ap = p; p += Bsz * 8 * Hdim;
  float* gh      = p; p += Bsz * 3072;
  float* part_gi = p; p += 4 * Bsz * 3072;
  unsigned short* up = (unsigned short*)p;
  unsigned short* ub  = up; up += 1024 * 1024;
  unsigned short* lb  = up; up += (size_t)Cctx * Bsz * Hdim;
  unsigned short* h0b = up; up += Bsz * Hdim;
  unsigned short* hnb = up; up += Bsz * Hdim;
  unsigned short* xb  = up; up += Bsz * 3072;

  prep<<<dim3(32, 32, 3), 256, 0, stream>>>(dyna_W, dyna_U, hidden, Wt, ub, h0b);
  conv_bf16<<<(Cctx * Bsz * Hdim) / 2048, 256, 0, stream>>>(lch, lb);
  hipMemsetAsync(scores, 0, Bsz * Cctx * sizeof(float), stream);

  // q = h0@Wt, gh = h0@W_hh^T + b_hh
  qgh_gemm<<<256, 64, 0, stream>>>(h0b, Wt, W_hh, b_hh, q, gh);

  // scores += tanh(q + lch@U) . v
  gemm_att<<<dim3(8, 104), 256, 0, stream>>>(lb, ub, q, dyna_v, scores);

  softmax_applied<<<dim3(8, Bsz), 256, 0, stream>>>(scores, pad, ch, part_ap);
  build_xb<<<dim3(12, Bsz), 256, 0, stream>>>(input, topic, part_ap, xb);

  // gi partials (K split x4)
  gi_split<<<dim3(192, 4), 64, 0, stream>>>(xb, W_ih, part_gi);

  gru_gate<<<(Bsz * Hdim) / 256, 256, 0, stream>>>(part_gi, b_ih, gh, hidden, out_h, hnb);

  // logits = h_new @ W_out^T + b_out
  stream_gemm<2><<<(Vv + 15) / 16, 64, 0, stream>>>(hnb, W_out, Vv, Hdim, b_out, out);

  lse_fused<<<Bsz, 1024, 0, stream>>>(out);
}

// Round 4
// 247.641 us; speedup vs baseline: 3.7941x; 1.1220x over previous
//
#include <hip/hip_runtime.h>
#include <hip/hip_bf16.h>
#include <math.h>

constexpr int Bsz = 64, Cctx = 200, Hdim = 1024, Vv = 50257;
constexpr float NEG_INF_V = -100000.0f;

typedef __attribute__((ext_vector_type(8))) short s16x8;
typedef __attribute__((ext_vector_type(4))) float fx4;
typedef unsigned int u32;

__device__ __forceinline__ unsigned short f2bf(float f) {
  unsigned int u = __builtin_bit_cast(unsigned int, f);
  unsigned int r = (u + 0x7fffu + ((u >> 16) & 1u)) >> 16;
  return (unsigned short)r;
}

__device__ __forceinline__ float fast_tanh(float x) {
  float e2 = __expf(2.f * x);
  return 1.f - 2.f / (e2 + 1.f);
}

__device__ __forceinline__ void gl_lds16(const unsigned short* g, unsigned short* l) {
  __builtin_amdgcn_global_load_lds(
      (const __attribute__((address_space(1))) u32*)g,
      (__attribute__((address_space(3))) u32*)l, 16, 0, 0);
}

// ---------- attention GEMM: dbuf + T2 both-sides XOR swizzle + prefetch ----------
// A(12800,1024)bf16 @ B(1024,1024)bf16^T, fused tanh(.+q).v epilogue -> scores atomics
__global__ __launch_bounds__(256)
void gemm_att(const unsigned short* __restrict__ Ab, const unsigned short* __restrict__ Bb,
              const float* __restrict__ qmat, const float* __restrict__ vvec,
              float* __restrict__ scores) {
  __shared__ unsigned short As[2][128 * 64];
  __shared__ unsigned short Bs[2][128 * 64];
  // XCD remap: xcd owns 13 M-tiles x 8 N-tiles; blocks sharing an A-tile share an XCD
  int f = blockIdx.x + blockIdx.y * 8;
  int xcd = f & 7, jj = f >> 3;
  int my = xcd + 8 * (jj % 13), mx = jj / 13;
  if (my >= 100) return;
  const int bm0 = my * 128, bn0 = mx * 128;
  const int tid = threadIdx.x, lane = tid & 63, wid = tid >> 6;
  const int wm0 = (wid >> 1) * 64, wn0 = (wid & 1) * 64;
  const int ar = lane & 15;       // row within 16-frag
  const int q4 = lane >> 4;       // 16B chunk selector
  const int sw = ar & 7;          // read-side XOR mask

  // stage: thread s writes LDS linear chunk s (16B); source chunk pre-swizzled
  auto STAGE = [&](int buf, int kt) {
    #pragma unroll
    for (int i = 0; i < 4; ++i) {
      int s = tid + i * 256;
      int row = s >> 3;
      int sc = ((s & 7) ^ (row & 7)) * 8;
      gl_lds16(&Ab[(size_t)(bm0 + row) * Hdim + kt + sc], &As[buf][s * 8]);
    }
    #pragma unroll
    for (int i = 0; i < 4; ++i) {
      int s = tid + i * 256;
      int row = s >> 3;
      int sc = ((s & 7) ^ (row & 7)) * 8;
      gl_lds16(&Bb[(size_t)(bn0 + row) * Hdim + kt + sc], &Bs[buf][s * 8]);
    }
  };

  fx4 acc[4][4] = {};
  int buf = 0;
  STAGE(0, 0);
  __syncthreads();

  for (int t = 0; t < 16; ++t) {
    if (t < 15) STAGE(buf ^ 1, (t + 1) * 64);
    asm volatile("" ::: "memory");       // keep prefetch issue ahead of compute
    #pragma unroll
    for (int kk = 0; kk < 2; ++kk) {
      s16x8 a[4], b[4];
      #pragma unroll
      for (int i = 0; i < 4; ++i)
        a[i] = *reinterpret_cast<const s16x8*>(
            &As[buf][(wm0 + i * 16 + ar) * 64 + (((kk * 4 + q4) ^ sw) * 8)]);
      #pragma unroll
      for (int j2 = 0; j2 < 4; ++j2)
        b[j2] = *reinterpret_cast<const s16x8*>(
            &Bs[buf][(wn0 + j2 * 16 + ar) * 64 + (((kk * 4 + q4) ^ sw) * 8)]);
      #pragma unroll
      for (int i = 0; i < 4; ++i)
        #pragma unroll
        for (int j2 = 0; j2 < 4; ++j2)
          acc[i][j2] = __builtin_amdgcn_mfma_f32_16x16x32_bf16(a[i], b[j2], acc[i][j2], 0, 0, 0);
    }
    __syncthreads();                     // vmcnt(0) drain lands AFTER compute
    buf ^= 1;
  }

  const int rg = q4 * 4, cg = ar;
  #pragma unroll
  for (int i = 0; i < 4; ++i) {
    #pragma unroll
    for (int p = 0; p < 4; ++p) {
      int mg = bm0 + wm0 + i * 16 + rg + p;
      int brow = mg & 63;
      float rs = 0.f;
      #pragma unroll
      for (int j2 = 0; j2 < 4; ++j2) {
        int ng = bn0 + wn0 + j2 * 16 + cg;
        float t = fast_tanh(acc[i][j2][p] + qmat[brow * Hdim + ng]);
        rs += t * vvec[ng];
      }
      rs += __shfl_xor(rs, 1); rs += __shfl_xor(rs, 2);
      rs += __shfl_xor(rs, 4); rs += __shfl_xor(rs, 8);
      if (cg == 0) atomicAdd(&scores[brow * Cctx + (mg >> 6)], rs);
    }
  }
}

// ---------- 1-wave streaming GEMM body: C(64,Ncols) = A(64,K)bf16 @ B(.,K)f32^T ----
__device__ __forceinline__ void stream_body(const unsigned short* ap, const float* bp,
                                            int K, fx4 acc[4]) {
  float4 b0 = *reinterpret_cast<const float4*>(bp);
  float4 b1 = *reinterpret_cast<const float4*>(bp + 4);
  float4 b2 = *reinterpret_cast<const float4*>(bp + 32);
  float4 b3 = *reinterpret_cast<const float4*>(bp + 36);
  for (int kt = 0; kt < K; kt += 64) {
    float4 c0 = b0, c1 = b1, c2 = b2, c3 = b3;
    if (kt + 64 < K) {
      b0 = *reinterpret_cast<const float4*>(bp + kt + 64);
      b1 = *reinterpret_cast<const float4*>(bp + kt + 68);
      b2 = *reinterpret_cast<const float4*>(bp + kt + 96);
      b3 = *reinterpret_cast<const float4*>(bp + kt + 100);
    }
    s16x8 bf0, bf1;
    bf0[0] = (short)f2bf(c0.x); bf0[1] = (short)f2bf(c0.y);
    bf0[2] = (short)f2bf(c0.z); bf0[3] = (short)f2bf(c0.w);
    bf0[4] = (short)f2bf(c1.x); bf0[5] = (short)f2bf(c1.y);
    bf0[6] = (short)f2bf(c1.z); bf0[7] = (short)f2bf(c1.w);
    bf1[0] = (short)f2bf(c2.x); bf1[1] = (short)f2bf(c2.y);
    bf1[2] = (short)f2bf(c2.z); bf1[3] = (short)f2bf(c2.w);
    bf1[4] = (short)f2bf(c3.x); bf1[5] = (short)f2bf(c3.y);
    bf1[6] = (short)f2bf(c3.z); bf1[7] = (short)f2bf(c3.w);
    #pragma unroll
    for (int i = 0; i < 4; ++i) {
      s16x8 af = *reinterpret_cast<const s16x8*>(ap + (size_t)i * 16 * K + kt);
      acc[i] = __builtin_amdgcn_mfma_f32_16x16x32_bf16(af, bf0, acc[i], 0, 0, 0);
    }
    #pragma unroll
    for (int i = 0; i < 4; ++i) {
      s16x8 af = *reinterpret_cast<const s16x8*>(ap + (size_t)i * 16 * K + kt + 32);
      acc[i] = __builtin_amdgcn_mfma_f32_16x16x32_bf16(af, bf1, acc[i], 0, 0, 0);
    }
  }
}

template<int EPI>  // 0: plain, 2: +bias
__global__ __launch_bounds__(64)
void stream_gemm(const unsigned short* __restrict__ Ab,
                 const float* __restrict__ Bm, int N, int K,
                 const float* __restrict__ bias, float* __restrict__ Cout) {
  const int lane = threadIdx.x;
  const int n0 = blockIdx.x * 16;
  const int c = lane & 15, qq = lane >> 4;
  const int brow = min(n0 + c, N - 1);
  fx4 acc[4] = {};
  stream_body(Ab + (size_t)c * K + qq * 8, Bm + (size_t)brow * K + qq * 8, K, acc);
  const int n = n0 + c;
  if (n < N) {
    float bv = (EPI == 2) ? bias[n] : 0.f;
    #pragma unroll
    for (int i = 0; i < 4; ++i)
      #pragma unroll
      for (int p = 0; p < 4; ++p)
        Cout[(size_t)(i * 16 + qq * 4 + p) * N + n] = acc[i][p] + bv;
  }
}

// q = h0@Wt (N=1024) and gh = h0@W_hh^T + b_hh (N=3072), one wave per 16 cols
__global__ __launch_bounds__(64)
void qgh_gemm(const unsigned short* __restrict__ h0b, const float* __restrict__ Wt,
              const float* __restrict__ Whh, const float* __restrict__ bhh,
              float* __restrict__ q, float* __restrict__ gh) {
  const int lane = threadIdx.x;
  const int gw = blockIdx.x;            // 0..255
  const bool isq = gw < 64;
  const int n0 = isq ? gw * 16 : (gw - 64) * 16;
  const int N = isq ? 1024 : 3072;
  const float* B = isq ? Wt : Whh;
  const int c = lane & 15, qq = lane >> 4;
  fx4 acc[4] = {};
  stream_body(h0b + (size_t)c * 1024 + qq * 8, B + (size_t)(n0 + c) * 1024 + qq * 8, 1024, acc);
  const int n = n0 + c;
  float bv = isq ? 0.f : bhh[n];
  float* C = isq ? q : gh;
  #pragma unroll
  for (int i = 0; i < 4; ++i)
    #pragma unroll
    for (int p = 0; p < 4; ++p)
      C[(size_t)(i * 16 + qq * 4 + p) * N + n] = acc[i][p] + bv;
}

// gi partials, K split in 4 chunks of 768: part[w][64][3072]
__global__ __launch_bounds__(64)
void gi_split(const unsigned short* __restrict__ xb, const float* __restrict__ Wih,
              float* __restrict__ part) {
  const int lane = threadIdx.x;
  const int t = blockIdx.x;             // n-tile 0..191
  const int w = blockIdx.y;             // k-chunk 0..3
  const int c = lane & 15, qq = lane >> 4;
  constexpr int K = 3072, CH = 768;
  const float* bp = Wih + (size_t)(t * 16 + c) * K + w * CH + qq * 8;
  const unsigned short* ap = xb + (size_t)c * K + w * CH + qq * 8;
  fx4 acc[4] = {};
  float4 b0 = *reinterpret_cast<const float4*>(bp);
  float4 b1 = *reinterpret_cast<const float4*>(bp + 4);
  float4 b2 = *reinterpret_cast<const float4*>(bp + 32);
  float4 b3 = *reinterpret_cast<const float4*>(bp + 36);
  for (int kt = 0; kt < CH; kt += 64) {
    float4 c0 = b0, c1 = b1, c2 = b2, c3 = b3;
    if (kt + 64 < CH) {
      b0 = *reinterpret_cast<const float4*>(bp + kt + 64);
      b1 = *reinterpret_cast<const float4*>(bp + kt + 68);
      b2 = *reinterpret_cast<const float4*>(bp + kt + 96);
      b3 = *reinterpret_cast<const float4*>(bp + kt + 100);
    }
    s16x8 bf0, bf1;
    bf0[0] = (short)f2bf(c0.x); bf0[1] = (short)f2bf(c0.y);
    bf0[2] = (short)f2bf(c0.z); bf0[3] = (short)f2bf(c0.w);
    bf0[4] = (short)f2bf(c1.x); bf0[5] = (short)f2bf(c1.y);
    bf0[6] = (short)f2bf(c1.z); bf0[7] = (short)f2bf(c1.w);
    bf1[0] = (short)f2bf(c2.x); bf1[1] = (short)f2bf(c2.y);
    bf1[2] = (short)f2bf(c2.z); bf1[3] = (short)f2bf(c2.w);
    bf1[4] = (short)f2bf(c3.x); bf1[5] = (short)f2bf(c3.y);
    bf1[6] = (short)f2bf(c3.z); bf1[7] = (short)f2bf(c3.w);
    #pragma unroll
    for (int i = 0; i < 4; ++i) {
      s16x8 af = *reinterpret_cast<const s16x8*>(ap + (size_t)i * 16 * K + kt);
      acc[i] = __builtin_amdgcn_mfma_f32_16x16x32_bf16(af, bf0, acc[i], 0, 0, 0);
    }
    #pragma unroll
    for (int i = 0; i < 4; ++i) {
      s16x8 af = *reinterpret_cast<const s16x8*>(ap + (size_t)i * 16 * K + kt + 32);
      acc[i] = __builtin_amdgcn_mfma_f32_16x16x32_bf16(af, bf1, acc[i], 0, 0, 0);
    }
  }
  float* po = part + (size_t)w * 64 * 3072;
  const int n = t * 16 + c;
  #pragma unroll
  for (int i = 0; i < 4; ++i)
    #pragma unroll
    for (int p = 0; p < 4; ++p)
      po[(size_t)(i * 16 + qq * 4 + p) * 3072 + n] = acc[i][p];
}

// ---------- prep: W transpose (f32), U transpose (bf16), h0 conv ----------
__global__ __launch_bounds__(256)
void prep(const float* __restrict__ dW, const float* __restrict__ dU,
          const float* __restrict__ h0, float* __restrict__ Wt,
          unsigned short* __restrict__ ub, unsigned short* __restrict__ h0b) {
  const int z = blockIdx.z;
  const int tx = threadIdx.x & 31, ty = threadIdx.x >> 5;   // 32x8
  if (z < 2) {
    __shared__ float t[32][33];
    const float* in = z ? dU : dW;
    int bx = blockIdx.x * 32, by = blockIdx.y * 32;
    #pragma unroll
    for (int r = 0; r < 32; r += 8) t[ty + r][tx] = in[(size_t)(by + ty + r) * 1024 + bx + tx];
    __syncthreads();
    if (z == 0) {
      #pragma unroll
      for (int r = 0; r < 32; r += 8) Wt[(size_t)(bx + ty + r) * 1024 + by + tx] = t[tx][ty + r];
    } else {
      #pragma unroll
      for (int r = 0; r < 32; r += 8) ub[(size_t)(bx + ty + r) * 1024 + by + tx] = f2bf(t[tx][ty + r]);
    }
  } else {
    if (blockIdx.y) return;
    size_t i = (size_t)(blockIdx.x * 256 + threadIdx.x) * 8;   // 64*1024 total
    float4 a = *reinterpret_cast<const float4*>(h0 + i);
    float4 b = *reinterpret_cast<const float4*>(h0 + i + 4);
    s16x8 h;
    h[0] = (short)f2bf(a.x); h[1] = (short)f2bf(a.y); h[2] = (short)f2bf(a.z); h[3] = (short)f2bf(a.w);
    h[4] = (short)f2bf(b.x); h[5] = (short)f2bf(b.y); h[6] = (short)f2bf(b.z); h[7] = (short)f2bf(b.w);
    *reinterpret_cast<s16x8*>(h0b + i) = h;
  }
}

__global__ void conv_bf16(const float* __restrict__ in, unsigned short* __restrict__ out) {
  size_t i = (size_t)(blockIdx.x * 256 + threadIdx.x) * 8;
  float4 a = *reinterpret_cast<const float4*>(in + i);
  float4 b = *reinterpret_cast<const float4*>(in + i + 4);
  s16x8 h;
  h[0] = (short)f2bf(a.x); h[1] = (short)f2bf(a.y); h[2] = (short)f2bf(a.z); h[3] = (short)f2bf(a.w);
  h[4] = (short)f2bf(b.x); h[5] = (short)f2bf(b.y); h[6] = (short)f2bf(b.z); h[7] = (short)f2bf(b.w);
  *reinterpret_cast<s16x8*>(out + i) = h;
}

// ---------- softmax (redundant per g) + applied partial ----------
__global__ __launch_bounds__(256)
void softmax_applied(const float* __restrict__ scores, const int* __restrict__ pad,
                     const float* __restrict__ ch, float* __restrict__ part) {
  const int g = blockIdx.x, b = blockIdx.y, t = threadIdx.x;
  const int lane = t & 63, w = t >> 6;
  __shared__ float at[256];
  __shared__ float red[8];
  float sv = 0.f, v = -3.4e38f;
  if (t < Cctx) { sv = pad[b * Cctx + t] ? NEG_INF_V : scores[b * Cctx + t]; v = sv; }
  #pragma unroll
  for (int o = 1; o < 64; o <<= 1) v = fmaxf(v, __shfl_xor(v, o));
  if (lane == 0) red[w] = v;
  __syncthreads();
  float m = fmaxf(fmaxf(red[0], red[1]), fmaxf(red[2], red[3]));
  float e = (t < Cctx) ? expf(sv - m) : 0.f;
  float s = e;
  #pragma unroll
  for (int o = 1; o < 64; o <<= 1) s += __shfl_xor(s, o);
  if (lane == 0) red[4 + w] = s;
  __syncthreads();
  float tot = red[4] + red[5] + red[6] + red[7];
  at[t] = e / tot;
  __syncthreads();
  const int h = t * 4;
  float4 a4 = make_float4(0.f, 0.f, 0.f, 0.f);
  for (int c2 = g * 25; c2 < g * 25 + 25; ++c2) {
    float a = at[c2];
    float4 vv = *reinterpret_cast<const float4*>(&ch[((size_t)b * Cctx + c2) * Hdim + h]);
    a4.x += a * vv.x; a4.y += a * vv.y; a4.z += a * vv.z; a4.w += a * vv.w;
  }
  *reinterpret_cast<float4*>(&part[((size_t)b * 8 + g) * Hdim + h]) = a4;
}

__global__ void build_xb(const float* __restrict__ inp, const float* __restrict__ topic,
                         const float* __restrict__ part, unsigned short* __restrict__ xb) {
  int j = blockIdx.x * 256 + threadIdx.x;
  int b = blockIdx.y;
  float v;
  if (j < 1024) v = inp[b * 1024 + j];
  else if (j < 2048) v = topic[b * 1024 + (j - 1024)];
  else {
    const float* pp = &part[(size_t)b * 8 * Hdim + (j - 2048)];
    v = 0.f;
    #pragma unroll
    for (int g = 0; g < 8; ++g) v += pp[g * Hdim];
  }
  xb[(size_t)b * 3072 + j] = f2bf(v);
}

__global__ void gru_gate(const float* __restrict__ pgi, const float* __restrict__ bih,
                         const float* __restrict__ gh, const float* __restrict__ h0,
                         float* __restrict__ out_h, unsigned short* __restrict__ hnb) {
  int idx = blockIdx.x * 256 + threadIdx.x;
  int b = idx >> 10, j = idx & 1023;
  float gr = bih[j], gz = bih[1024 + j], gn = bih[2048 + j];
  const float* pb = pgi + (size_t)b * 3072;
  #pragma unroll
  for (int w = 0; w < 4; ++w) {
    const float* pw = pb + (size_t)w * 64 * 3072;
    gr += pw[j]; gz += pw[1024 + j]; gn += pw[2048 + j];
  }
  const float* ghb = gh + (size_t)b * 3072;
  float r = 1.f / (1.f + expf(-(gr + ghb[j])));
  float z = 1.f / (1.f + expf(-(gz + ghb[1024 + j])));
  float n = tanhf(gn + r * ghb[2048 + j]);
  float h = (1.f - z) * n + z * h0[idx];
  out_h[idx] = h;
  hnb[idx] = f2bf(h);
}

// ---------- fused log-softmax: max, sum, subtract (passes 2-3 are L2-hot) ----------
__global__ __launch_bounds__(1024)
void lse_fused(float* __restrict__ out) {
  const int b = blockIdx.x, t = threadIdx.x, lane = t & 63, w = t >> 6;
  __shared__ float red[16];
  float* row = out + (size_t)b * Vv;
  float m = -3.4e38f;
  for (int i = t; i < Vv; i += 1024) m = fmaxf(m, row[i]);
  #pragma unroll
  for (int o = 1; o < 64; o <<= 1) m = fmaxf(m, __shfl_xor(m, o));
  if (lane == 0) red[w] = m;
  __syncthreads();
  float mm = red[0];
  #pragma unroll
  for (int k = 1; k < 16; ++k) mm = fmaxf(mm, red[k]);
  float s = 0.f;
  for (int i = t; i < Vv; i += 1024) s += expf(row[i] - mm);
  #pragma unroll
  for (int o = 1; o < 64; o <<= 1) s += __shfl_xor(s, o);
  __syncthreads();
  if (lane == 0) red[w] = s;
  __syncthreads();
  float ss = 0.f;
  #pragma unroll
  for (int k = 0; k < 16; ++k) ss += red[k];
  float lse = mm + logf(ss);
  for (int i = t; i < Vv; i += 1024) row[i] -= lse;
}

extern "C" void kernel_launch(void* const* d_in, const int* in_sizes, int n_in,
                              void* d_out, int out_size, void* d_ws, size_t ws_size,
                              hipStream_t stream) {
  const float* input  = (const float*)d_in[0];
  const float* hidden = (const float*)d_in[1];
  const float* lch    = (const float*)d_in[2];
  const float* ch     = (const float*)d_in[3];
  const float* topic  = (const float*)d_in[4];
  const int*   pad    = (const int*)d_in[5];
  const float* dyna_W = (const float*)d_in[6];
  const float* dyna_U = (const float*)d_in[7];
  const float* dyna_v = (const float*)d_in[8];
  const float* W_ih   = (const float*)d_in[9];
  const float* W_hh   = (const float*)d_in[10];
  const float* b_ih   = (const float*)d_in[11];
  const float* b_hh   = (const float*)d_in[12];
  const float* W_out  = (const float*)d_in[13];
  const float* b_out  = (const float*)d_in[14];

  float* out   = (float*)d_out;
  float* out_h = out + (size_t)Bsz * Vv;

  float* p = (float*)d_ws;
  float* Wt      = p; p += 1024 * 1024;
  float* q       = p; p += Bsz * Hdim;
  float* scores  = p; p += Bsz * Cctx;
  float* part_ap = p; p += Bsz * 8 * Hdim;
  float* gh      = p; p += Bsz * 3072;
  float* part_gi = p; p += 4 * Bsz * 3072;
  unsigned short* up = (unsigned short*)p;
  unsigned short* ub  = up; up += 1024 * 1024;
  unsigned short* lb  = up; up += (size_t)Cctx * Bsz * Hdim;
  unsigned short* h0b = up; up += Bsz * Hdim;
  unsigned short* hnb = up; up += Bsz * Hdim;
  unsigned short* xb  = up; up += Bsz * 3072;

  prep<<<dim3(32, 32, 3), 256, 0, stream>>>(dyna_W, dyna_U, hidden, Wt, ub, h0b);
  conv_bf16<<<(Cctx * Bsz * Hdim) / 2048, 256, 0, stream>>>(lch, lb);
  hipMemsetAsync(scores, 0, Bsz * Cctx * sizeof(float), stream);

  // q = h0@Wt, gh = h0@W_hh^T + b_hh
  qgh_gemm<<<256, 64, 0, stream>>>(h0b, Wt, W_hh, b_hh, q, gh);

  // scores += tanh(q + lch@U) . v
  gemm_att<<<dim3(8, 104), 256, 0, stream>>>(lb, ub, q, dyna_v, scores);

  softmax_applied<<<dim3(8, Bsz), 256, 0, stream>>>(scores, pad, ch, part_ap);
  build_xb<<<dim3(12, Bsz), 256, 0, stream>>>(input, topic, part_ap, xb);

  // gi partials (K split x4)
  gi_split<<<dim3(192, 4), 64, 0, stream>>>(xb, W_ih, part_gi);

  gru_gate<<<(Bsz * Hdim) / 256, 256, 0, stream>>>(part_gi, b_ih, gh, hidden, out_h, hnb);

  // logits = h_new @ W_out^T + b_out
  stream_gemm<2><<<(Vv + 15) / 16, 64, 0, stream>>>(hnb, W_out, Vv, Hdim, b_out, out);

  lse_fused<<<Bsz, 1024, 0, stream>>>(out);
}